// Round 3
// baseline (32806.558 us; speedup 1.0000x reference)
//
#include <hip/hip_runtime.h>

#define BB 256     // batch
#define SS 128     // encoder seq len
#define FDIM 128   // input feature
#define HH 512     // hidden
#define H4 2048    // 4*H
#define TDEC 128   // decode steps
#define SOS_TOK 128

typedef short short8 __attribute__((ext_vector_type(8)));
typedef float f32x4 __attribute__((ext_vector_type(4)));

__device__ __forceinline__ float sigf(float x){ return 1.0f/(1.0f+__expf(-x)); }
__device__ __forceinline__ float tanh_f(float x){ return 1.0f - 2.0f/(__expf(2.0f*x)+1.0f); }

// round-to-nearest-even bf16 2-way split: x ~= hi + mid (16 mantissa bits kept)
__device__ __forceinline__ void split2(float x, unsigned& h, unsigned& m){
    union { float f; unsigned u; } a; a.f = x;
    h = (a.u + 0x7fffu + ((a.u>>16)&1u)) >> 16;
    union { unsigned u; float f; } hf; hf.u = h << 16;
    float r1 = x - hf.f;
    union { float f; unsigned u; } b; b.f = r1;
    m = (b.u + 0x7fffu + ((b.u>>16)&1u)) >> 16;
}

__device__ __forceinline__ void splitw8(float4 v, uint2& H, uint2& M){
    unsigned h0,m0,h1,m1,h2,m2,h3,m3;
    split2(v.x,h0,m0); split2(v.y,h1,m1); split2(v.z,h2,m2); split2(v.w,h3,m3);
    H.x = h0 | (h1<<16); H.y = h2 | (h3<<16);
    M.x = m0 | (m1<<16); M.y = m2 | (m3<<16);
}

// ---------------- weight split: fp32 [N][K] (opt gate-interleave, opt 2-src K-concat)
// -> 2 bf16 planes, k-panel layout [K/32][N][32] with 16B-part XOR swizzle
__global__ void split_w(const float* __restrict__ srcA, int KA,
                        const float* __restrict__ srcB, int KB, int ilv,
                        unsigned short* __restrict__ ph, unsigned short* __restrict__ pm,
                        int N){
    int k = blockIdx.x*128 + threadIdx.x;
    int n = blockIdx.y;
    int K = KA + KB;
    if (k >= K) return;
    int row = ilv ? ((n&3)*512 + (n>>2)) : n;
    float w = (k < KA) ? srcA[(size_t)row*KA + k] : srcB[(size_t)row*KB + (k-KA)];
    unsigned h,m; split2(w,h,m);
    size_t off = (size_t)(k>>5)*((size_t)N*32) + (size_t)n*32
               + ((((k>>3)&3) ^ (n&3))<<3) + (k&7);
    ph[off]=(unsigned short)h; pm[off]=(unsigned short)m;
}

__global__ void repack_b(float* __restrict__ dst, const float* __restrict__ src){
    int id = blockIdx.x*256 + threadIdx.x;
    if (id >= 2048) return;
    int g = id & 3, q = id >> 2;
    dst[id] = src[g*512 + q];
}

__global__ void init_tok(int* __restrict__ tok){ tok[threadIdx.x] = SOS_TOK; }

// ---------------- unified MFMA GEMM: C = A @ W^T (fp32 via 2-way bf16 split, 3 products)
// WG: 256 thr = 4 waves (2x2), wave tile 32x32 (2x2 frags of 16x16x32), WG tile 64x64.
// A: fp32, up to 3 K-segments (A0 general strides + opt tok row-indirection; A1/A2 stride 512).
// W: prebuilt 2 bf16 planes [Ktot/32][Nld][32], swizzled.
// MODE 0: out = acc + bias (+relu), fp32, row addr (r&255)*oB+(r>>8)*oT
// MODE 2: fused LSTM cell: z = acc + (xz ? xz[r][gc] : bias[gc]); gates via shfl_xor; writes c_io, seqo
#define MM3(AH,AM,BH,BM,C) \
  C = __builtin_amdgcn_mfma_f32_16x16x32_bf16(AH,BH,C,0,0,0); \
  C = __builtin_amdgcn_mfma_f32_16x16x32_bf16(AH,BM,C,0,0,0); \
  C = __builtin_amdgcn_mfma_f32_16x16x32_bf16(AM,BH,C,0,0,0);

template<int MODE>
__global__ __launch_bounds__(256) void mg(
    const float* __restrict__ A0, long a0B, long a0T,
    const float* __restrict__ A1, const float* __restrict__ A2,
    const int* __restrict__ tok, int ksh,
    const unsigned short* __restrict__ Wh, const unsigned short* __restrict__ Wm,
    int Nld, int Kc,
    const float* __restrict__ bias, int relu,
    float* __restrict__ out, long oB, long oT,
    const float* __restrict__ xz, float* __restrict__ c_io, float* __restrict__ seqo)
{
    __shared__ __align__(16) unsigned short sA[2][2][2048];
    __shared__ __align__(16) unsigned short sW[2][2][2048];
    const int tid = threadIdx.x;
    const int row0 = blockIdx.y * 64, col0 = blockIdx.x * 64;
    const int nk = Kc >> 5;

    f32x4 acc[2][2];
    acc[0][0] = (f32x4){0.f,0.f,0.f,0.f}; acc[0][1] = (f32x4){0.f,0.f,0.f,0.f};
    acc[1][0] = (f32x4){0.f,0.f,0.f,0.f}; acc[1][1] = (f32x4){0.f,0.f,0.f,0.f};

    // staging thread mapping: row sr (0..63), quarter q4 (2 float4 per thread)
    const int sr = tid >> 2, q4 = tid & 3;
    const int gr = row0 + sr;
    long ro0;
    if (tok){ int rr = tok[gr & 255]; ro0 = (long)rr * a0B; }
    else ro0 = (long)(gr & 255)*a0B + (long)(gr >> 8)*a0T;
    const long ro1 = (long)gr * 512;
    const size_t wbase = (size_t)col0*32 + (size_t)tid*8;
    const int swz = sr & 3;
    const int b0 = sr*32 + (q4 & 1)*4;
    const int p0s = ((q4>>1) ^ swz) << 3;
    const int p1s = ((2 + (q4>>1)) ^ swz) << 3;

    float4 va0, va1; uint4 vw0, vw1;

    auto issue = [&](int kt){
        int kg = kt*32;
        int seg = kg >> ksh;
        const float* sp = (seg==0)? A0 : ((seg==1)? A1 : A2);
        long ro = (seg==0)? ro0 : ro1;
        int ko = kg & ((1<<ksh)-1);
        const float* p = sp + ro + ko + q4*4;
        va0 = *(const float4*)p;
        va1 = *(const float4*)(p + 16);
        size_t wi = (size_t)(kg>>5)*((size_t)Nld*32) + wbase;
        vw0 = *(const uint4*)(Wh + wi);
        vw1 = *(const uint4*)(Wm + wi);
    };
    auto commit = [&](int buf){
        uint2 H,M;
        splitw8(va0,H,M);
        *(uint2*)&sA[buf][0][b0 + p0s] = H;
        *(uint2*)&sA[buf][1][b0 + p0s] = M;
        splitw8(va1,H,M);
        *(uint2*)&sA[buf][0][b0 + p1s] = H;
        *(uint2*)&sA[buf][1][b0 + p1s] = M;
        *(uint4*)&sW[buf][0][tid*8] = vw0;
        *(uint4*)&sW[buf][1][tid*8] = vw1;
    };

    const int wid = tid >> 6, lane = tid & 63;
    const int wy = wid >> 1, wx = wid & 1;
    const int l15 = lane & 15, l4 = lane >> 4;
    const int offA = (wy*32 + l15)*32 + ((l4 ^ (l15&3))<<3);
    const int offB = (wx*32 + l15)*32 + ((l4 ^ (l15&3))<<3);

    auto compute = [&](int buf){
        short8 a0h = *(const short8*)&sA[buf][0][offA];
        short8 a0m = *(const short8*)&sA[buf][1][offA];
        short8 a1h = *(const short8*)&sA[buf][0][offA+512];
        short8 a1m = *(const short8*)&sA[buf][1][offA+512];
        short8 b0h = *(const short8*)&sW[buf][0][offB];
        short8 b0m = *(const short8*)&sW[buf][1][offB];
        short8 b1h = *(const short8*)&sW[buf][0][offB+512];
        short8 b1m = *(const short8*)&sW[buf][1][offB+512];
        MM3(a0h,a0m,b0h,b0m,acc[0][0])
        MM3(a0h,a0m,b1h,b1m,acc[0][1])
        MM3(a1h,a1m,b0h,b0m,acc[1][0])
        MM3(a1h,a1m,b1h,b1m,acc[1][1])
    };

    issue(0);
    commit(0);
    __syncthreads();
    int buf = 0;
    for (int kt=0; kt<nk; ++kt){
        bool more = (kt+1 < nk);
        if (more) issue(kt+1);
        compute(buf);
        if (more) commit(buf^1);
        __syncthreads();
        buf ^= 1;
    }

    if (MODE == 0){
        #pragma unroll
        for (int fa=0; fa<2; fa++){
            #pragma unroll
            for (int fb=0; fb<2; fb++){
                int gc = col0 + wx*32 + fb*16 + l15;
                float bv = bias ? bias[gc] : 0.0f;
                #pragma unroll
                for (int i=0;i<4;i++){
                    int r = row0 + wy*32 + fa*16 + l4*4 + i;
                    float v = acc[fa][fb][i] + bv;
                    if (relu) v = fmaxf(v, 0.0f);
                    out[(size_t)(r&255)*oB + (size_t)(r>>8)*oT + gc] = v;
                }
            }
        }
    } else {
        #pragma unroll
        for (int fa=0; fa<2; fa++){
            #pragma unroll
            for (int fb=0; fb<2; fb++){
                int gc = col0 + wx*32 + fb*16 + l15;
                int q = gc >> 2, g = gc & 3;
                float ab = xz ? 0.0f : bias[gc];
                #pragma unroll
                for (int i=0;i<4;i++){
                    int r = row0 + wy*32 + fa*16 + l4*4 + i;
                    float addv = xz ? xz[(size_t)r*2048 + gc] : ab;
                    float z = acc[fa][fb][i] + addv;
                    float x1 = __shfl_xor(z, 1);
                    float x2 = __shfl_xor(z, 2);
                    float x3 = __shfl_xor(z, 3);
                    float zi = (g==0)?z :(g==1)?x1:(g==2)?x2:x3;
                    float zf = (g==1)?z :(g==0)?x1:(g==3)?x2:x3;
                    float zg = (g==2)?z :(g==3)?x1:(g==0)?x2:x3;
                    float zo = (g==3)?z :(g==2)?x1:(g==1)?x2:x3;
                    float co = c_io[(size_t)r*512 + q];
                    float cn = sigf(zf)*co + sigf(zi)*tanh_f(zg);
                    float hn = sigf(zo)*tanh_f(cn);
                    if (g == 1) c_io[(size_t)r*512 + q] = cn;
                    else if (g == 0) seqo[(size_t)r*512 + q] = hn;
                }
            }
        }
    }
}

// ---------------- fused fc1 + attention: ht = h2@fc1^T+b; scores(tanh)+softmax+context ----------------
__global__ __launch_bounds__(256) void attn_fc1(
    const float* __restrict__ h2,    // [B,512]
    const float* __restrict__ fc1w,  // [256,512]
    const float* __restrict__ fc1b,  // [256]
    const float* __restrict__ ot,    // [B,S,256]
    const float* __restrict__ enc,   // [S,B,H]
    const float* __restrict__ fc3,   // [256]
    float* __restrict__ ctx)         // [B,H]
{
    __shared__ float h2s[512], hts[256], f3s[256], wsm[SS];
    const int b = blockIdx.x, tid = threadIdx.x;
    h2s[tid]     = h2[(size_t)b*512 + tid];
    h2s[tid+256] = h2[(size_t)b*512 + tid + 256];
    f3s[tid] = fc3[tid];
    __syncthreads();
    // fc1 row: ht[tid] = sum_k h2[k]*fc1w[tid,k] + fc1b[tid]
    {
        const float4* wr = (const float4*)(fc1w + (size_t)tid*512);
        float s0=0.f, s1=0.f;
        #pragma unroll 4
        for (int k4=0; k4<128; k4+=2){
            float4 w0 = wr[k4], w1 = wr[k4+1];
            float4 hh0 = *(const float4*)&h2s[k4*4];
            float4 hh1 = *(const float4*)&h2s[k4*4+4];
            s0 = fmaf(w0.x,hh0.x,fmaf(w0.y,hh0.y,fmaf(w0.z,hh0.z,fmaf(w0.w,hh0.w,s0))));
            s1 = fmaf(w1.x,hh1.x,fmaf(w1.y,hh1.y,fmaf(w1.z,hh1.z,fmaf(w1.w,hh1.w,s1))));
        }
        hts[tid] = s0 + s1 + fc1b[tid];
    }
    __syncthreads();
    const int wave = tid >> 6, lane = tid & 63;
    const float* otb = ot + (size_t)b*SS*256;
    for (int i=0;i<32;i++){
        int s = wave*32 + i;
        float4 o = *(const float4*)&otb[(size_t)s*256 + lane*4];
        int d0 = lane*4;
        float v = f3s[d0+0]*tanh_f(o.x + hts[d0+0])
                + f3s[d0+1]*tanh_f(o.y + hts[d0+1])
                + f3s[d0+2]*tanh_f(o.z + hts[d0+2])
                + f3s[d0+3]*tanh_f(o.w + hts[d0+3]);
        #pragma unroll
        for (int off=32; off; off>>=1) v += __shfl_xor(v, off);
        if (lane == 0) wsm[s] = v;
    }
    __syncthreads();
    if (tid < 64){
        float v0 = wsm[tid], v1 = wsm[tid+64];
        float m = fmaxf(v0, v1);
        #pragma unroll
        for (int off=32; off; off>>=1) m = fmaxf(m, __shfl_xor(m, off));
        float e0 = __expf(v0 - m), e1 = __expf(v1 - m);
        float ss = e0 + e1;
        #pragma unroll
        for (int off=32; off; off>>=1) ss += __shfl_xor(ss, off);
        float inv = 1.0f/ss;
        wsm[tid] = e0*inv; wsm[tid+64] = e1*inv;
    }
    __syncthreads();
    float a0=0.f, a1=0.f;
    const float* eb = enc + (size_t)b*HH;
    #pragma unroll 8
    for (int s=0;s<SS;s++){
        float w = wsm[s];
        const float* e = eb + (size_t)s*BB*HH;
        a0 = fmaf(w, e[tid],      a0);
        a1 = fmaf(w, e[tid+256],  a1);
    }
    ctx[(size_t)b*HH + tid]      = a0;
    ctx[(size_t)b*HH + tid+256]  = a1;
}

// ---------------- fused mlp3 + argmax: logits = hdd2@w3^T+b3; tok = argmax ----------------
__global__ __launch_bounds__(128) void mlp3_argmax(
    const float* __restrict__ hdd2,  // [B,256]
    const float* __restrict__ w3,    // [128,256]
    const float* __restrict__ b3,    // [128]
    float* __restrict__ outp,        // [B,128] (this step's logits slice)
    int* __restrict__ tok)
{
    __shared__ float hs[256], lg[128];
    const int b = blockIdx.x, tid = threadIdx.x;
    hs[tid]     = hdd2[(size_t)b*256 + tid];
    hs[tid+128] = hdd2[(size_t)b*256 + tid + 128];
    __syncthreads();
    const float4* wr = (const float4*)(w3 + (size_t)tid*256);
    float s0=0.f, s1=0.f;
    #pragma unroll 4
    for (int k4=0; k4<64; k4+=2){
        float4 w0 = wr[k4], w1 = wr[k4+1];
        float4 h0 = *(const float4*)&hs[k4*4];
        float4 h1 = *(const float4*)&hs[k4*4+4];
        s0 = fmaf(w0.x,h0.x,fmaf(w0.y,h0.y,fmaf(w0.z,h0.z,fmaf(w0.w,h0.w,s0))));
        s1 = fmaf(w1.x,h1.x,fmaf(w1.y,h1.y,fmaf(w1.z,h1.z,fmaf(w1.w,h1.w,s1))));
    }
    float v = s0 + s1 + b3[tid];
    outp[(size_t)b*128 + tid] = v;
    lg[tid] = v;
    __syncthreads();
    if (tid < 64){
        float v0 = lg[tid], v1 = lg[tid+64];
        float bv; int bi;
        if (v1 > v0){ bv = v1; bi = tid+64; } else { bv = v0; bi = tid; }
        #pragma unroll
        for (int off=32; off; off>>=1){
            float ov = __shfl_xor(bv, off);
            int   oi = __shfl_xor(bi, off);
            if (ov > bv || (ov == bv && oi < bi)){ bv = ov; bi = oi; }
        }
        if (tid == 0) tok[b] = bi;
    }
}

extern "C" void kernel_launch(void* const* d_in, const int* in_sizes, int n_in,
                              void* d_out, int out_size, void* d_ws, size_t ws_size,
                              hipStream_t stream)
{
    (void)in_sizes; (void)n_in; (void)out_size;
    const float* l2      = (const float*)d_in[0];
    const float* e_wih[3] = {(const float*)d_in[1],(const float*)d_in[4],(const float*)d_in[7]};
    const float* e_whh[3] = {(const float*)d_in[2],(const float*)d_in[5],(const float*)d_in[8]};
    const float* e_b[3]   = {(const float*)d_in[3],(const float*)d_in[6],(const float*)d_in[9]};
    const float* d_wih[3] = {(const float*)d_in[10],(const float*)d_in[13],(const float*)d_in[16]};
    const float* d_whh[3] = {(const float*)d_in[11],(const float*)d_in[14],(const float*)d_in[17]};
    const float* d_b[3]   = {(const float*)d_in[12],(const float*)d_in[15],(const float*)d_in[18]};
    const float* emb   = (const float*)d_in[19];
    const float* fc1_w = (const float*)d_in[20]; const float* fc1_b = (const float*)d_in[21];
    const float* fc2_w = (const float*)d_in[22]; const float* fc2_b = (const float*)d_in[23];
    const float* fc3_w = (const float*)d_in[24];
    const float* w1 = (const float*)d_in[25]; const float* b1 = (const float*)d_in[26];
    const float* w2 = (const float*)d_in[27]; const float* b2 = (const float*)d_in[28];
    const float* w3 = (const float*)d_in[29]; const float* b3 = (const float*)d_in[30];
    float* out = (float*)d_out;

    float* base = (float*)d_ws;
    size_t off = 0;
    auto alloc = [&](size_t n)->float*{ float* r = base + off; off = (off + n + 63) & ~(size_t)63; return r; };

    // ---- weight plane table: {srcA, KA, srcB, KB, interleave, N} ----
    struct WSpec { const float* a; int ka; const float* b; int kb; int ilv; int n; };
    WSpec ws[13] = {
        {e_wih[0],128, nullptr,0, 1,2048}, {e_wih[1],512, nullptr,0, 1,2048}, {e_wih[2],512, nullptr,0, 1,2048},
        {e_whh[0],512, nullptr,0, 1,2048}, {e_whh[1],512, nullptr,0, 1,2048}, {e_whh[2],512, nullptr,0, 1,2048},
        {d_wih[0],1024, d_whh[0],512, 1,2048}, {d_wih[1],512, d_whh[1],512, 1,2048}, {d_wih[2],512, d_whh[2],512, 1,2048},
        {fc2_w,512, nullptr,0, 0,256},
        {w1,1024, nullptr,0, 0,512}, {w2,512, nullptr,0, 0,256}, {w3,256, nullptr,0, 0,128}
    };
    unsigned short* wp[13][2];
    for (int i=0;i<13;i++){
        size_t sz = (size_t)(ws[i].ka + ws[i].kb) * ws[i].n;   // ushorts per plane
        float* blk = alloc(sz);                                 // 2 planes = sz floats
        wp[i][0] = (unsigned short*)blk;
        wp[i][1] = wp[i][0] + sz;
    }
    float* br_e[3]; for (int l=0;l<3;l++) br_e[l] = alloc(2048);
    float* br_d[3]; for (int l=0;l<3;l++) br_d[l] = alloc(2048);

    float* seq   = alloc((size_t)SS*BB*HH);      // encoder h sequence (fp32)
    float* ot    = alloc((size_t)BB*SS*256);     // [b][s][256]
    float* zbuf  = alloc((size_t)BB*HH);
    float* cbuf[3]; for (int l=0;l<3;l++) cbuf[l] = alloc((size_t)BB*HH);
    float* hbuf[3][2];
    for (int l=0;l<3;l++) for (int p=0;p<2;p++) hbuf[l][p] = alloc((size_t)BB*HH);
    float* ctx  = alloc((size_t)BB*HH);
    float* hdd1 = alloc((size_t)BB*512);
    float* hdd2 = alloc((size_t)BB*256);
    int*   tok  = (int*)alloc(256);

    // xz chunk buffer from remaining workspace
    size_t remain = (ws_size/4 > off) ? (ws_size/4 - off) : 0;
    int CH = 4;
    if      (remain >= (size_t)32*BB*H4) CH = 32;
    else if (remain >= (size_t)16*BB*H4) CH = 16;
    else if (remain >= (size_t) 8*BB*H4) CH = 8;
    float* xz = base + off;

    // ---- build weight planes + biases ----
    for (int i=0;i<13;i++){
        int K = ws[i].ka + ws[i].kb;
        hipLaunchKernelGGL(split_w, dim3((K+127)/128, ws[i].n), dim3(128), 0, stream,
                           ws[i].a, ws[i].ka, ws[i].b, ws[i].kb, ws[i].ilv,
                           wp[i][0], wp[i][1], ws[i].n);
    }
    for (int l=0;l<3;l++){
        hipLaunchKernelGGL(repack_b, dim3(8), dim3(256), 0, stream, br_e[l], e_b[l]);
        hipLaunchKernelGGL(repack_b, dim3(8), dim3(256), 0, stream, br_d[l], d_b[l]);
    }
    hipMemsetAsync(zbuf, 0, (size_t)BB*HH*4, stream);
    for (int l=0;l<3;l++) hipMemsetAsync(cbuf[l], 0, (size_t)BB*HH*4, stream);
    hipMemsetAsync(ctx, 0, (size_t)BB*HH*4, stream);

    // ---- encoder: chunked x-transform (MODE0) + sequential fused-cell steps (MODE2) ----
    for (int l=0;l<3;l++){
        const int Kih = (l==0)? FDIM : HH;
        const int nch = SS / CH;
        for (int tc=0; tc<nch; tc++){
            const float* A0; long sB, sT;
            if (l == 0){ A0 = l2 + (size_t)tc*CH*FDIM; sB = (long)SS*FDIM; sT = FDIM; }
            else       { A0 = seq + (size_t)tc*CH*BB*HH; sB = HH; sT = (long)BB*HH; }
            hipLaunchKernelGGL((mg<0>), dim3(32, CH*4), dim3(256), 0, stream,
                A0, sB, sT, (const float*)nullptr, (const float*)nullptr, (const int*)nullptr, 30,
                wp[l][0], wp[l][1], 2048, Kih,
                br_e[l], 0, xz, (long)H4, (long)BB*H4,
                (const float*)nullptr, (float*)nullptr, (float*)nullptr);
            for (int ti=0; ti<CH; ti++){
                int t = tc*CH + ti;
                const float* hp = (t==0) ? zbuf : seq + (size_t)(t-1)*BB*HH;
                hipLaunchKernelGGL((mg<2>), dim3(32, 4), dim3(256), 0, stream,
                    hp, (long)HH, 0L, (const float*)nullptr, (const float*)nullptr, (const int*)nullptr, 30,
                    wp[3+l][0], wp[3+l][1], 2048, HH,
                    (const float*)nullptr, 0, (float*)nullptr, 0L, 0L,
                    xz + (size_t)ti*BB*H4, cbuf[l], seq + (size_t)t*BB*HH);
            }
        }
        hipMemcpyAsync(hbuf[l][0], seq + (size_t)(SS-1)*BB*HH, (size_t)BB*HH*4,
                       hipMemcpyDeviceToDevice, stream);
    }

    // ---- ot = enc_outs @ fc2^T + fc2_b  ([b][s][256]) ----
    hipLaunchKernelGGL((mg<0>), dim3(4, 512), dim3(256), 0, stream,
        seq, (long)HH, (long)BB*HH, (const float*)nullptr, (const float*)nullptr, (const int*)nullptr, 30,
        wp[9][0], wp[9][1], 256, HH,
        fc2_b, 0, ot, (long)SS*256, 256L,
        (const float*)nullptr, (float*)nullptr, (float*)nullptr);

    // ---- decoder: 7 kernels per step ----
    hipLaunchKernelGGL(init_tok, dim3(1), dim3(256), 0, stream, tok);
    for (int t=0; t<TDEC; t++){
        const int p = t & 1;
        // L0: [emb[tok] | ctx | h0_prev], K=1536, fused cell
        hipLaunchKernelGGL((mg<2>), dim3(32, 4), dim3(256), 0, stream,
            emb, (long)HH, 0L, ctx, hbuf[0][p], tok, 9,
            wp[6][0], wp[6][1], 2048, 3*HH,
            br_d[0], 0, (float*)nullptr, 0L, 0L,
            (const float*)nullptr, cbuf[0], hbuf[0][p^1]);
        // L1: [h0_new | h1_prev], K=1024, fused cell
        hipLaunchKernelGGL((mg<2>), dim3(32, 4), dim3(256), 0, stream,
            hbuf[0][p^1], (long)HH, 0L, hbuf[1][p], (const float*)nullptr, (const int*)nullptr, 9,
            wp[7][0], wp[7][1], 2048, 2*HH,
            br_d[1], 0, (float*)nullptr, 0L, 0L,
            (const float*)nullptr, cbuf[1], hbuf[1][p^1]);
        // L2: [h1_new | h2_prev], K=1024, fused cell
        hipLaunchKernelGGL((mg<2>), dim3(32, 4), dim3(256), 0, stream,
            hbuf[1][p^1], (long)HH, 0L, hbuf[2][p], (const float*)nullptr, (const int*)nullptr, 9,
            wp[8][0], wp[8][1], 2048, 2*HH,
            br_d[2], 0, (float*)nullptr, 0L, 0L,
            (const float*)nullptr, cbuf[2], hbuf[2][p^1]);
        // fc1 + attention -> ctx
        hipLaunchKernelGGL(attn_fc1, dim3(BB), dim3(256), 0, stream,
            hbuf[2][p^1], fc1_w, fc1_b, ot, seq, fc3_w, ctx);
        // mlp1: [h2 | ctx] @ w1^T + b1, relu, K=1024, N=512
        hipLaunchKernelGGL((mg<0>), dim3(8, 4), dim3(256), 0, stream,
            hbuf[2][p^1], (long)HH, 0L, ctx, (const float*)nullptr, (const int*)nullptr, 9,
            wp[10][0], wp[10][1], 512, 2*HH,
            b1, 1, hdd1, 512L, 0L,
            (const float*)nullptr, (float*)nullptr, (float*)nullptr);
        // mlp2: hdd1 @ w2^T + b2, relu, K=512, N=256
        hipLaunchKernelGGL((mg<0>), dim3(4, 4), dim3(256), 0, stream,
            hdd1, 512L, 0L, (const float*)nullptr, (const float*)nullptr, (const int*)nullptr, 30,
            wp[11][0], wp[11][1], 256, HH,
            b2, 1, hdd2, 256L, 0L,
            (const float*)nullptr, (float*)nullptr, (float*)nullptr);
        // mlp3 + argmax -> logits, tok
        hipLaunchKernelGGL(mlp3_argmax, dim3(BB), dim3(128), 0, stream,
            hdd2, w3, b3, out + (size_t)t*BB*128, tok);
    }
}